// Round 13
// baseline (501.482 us; speedup 1.0000x reference)
//
#include <hip/hip_runtime.h>

#define BATCH 131072

typedef __attribute__((ext_vector_type(8))) __bf16 bf16x8;
typedef __attribute__((ext_vector_type(16))) float f32x16;
typedef __attribute__((ext_vector_type(2))) float f32x2;

__constant__ int FOFF[23] = {0,4,8,12,16,20,24,28,32,36,40,44,48,50,52,53,57,58,59,60,61,62,63};
__constant__ int FDIM[23] = {4,4,4,4,4,4,4,4,4,4,4,4,2,2,1,4,1,1,1,1,1,1,2};

__device__ __forceinline__ unsigned short f2bf(float f){
  unsigned int u = __float_as_uint(f);
  u += 0x7fffu + ((u>>16)&1u);   // RNE
  return (unsigned short)(u>>16);
}
__device__ __forceinline__ unsigned int packpair(float a, float b){
  return (unsigned int)f2bf(a) | ((unsigned int)f2bf(b)<<16);
}
__device__ __forceinline__ float bflo(unsigned int u){ return __uint_as_float(u<<16); }
__device__ __forceinline__ float bfhi(unsigned int u){ return __uint_as_float(u & 0xffff0000u); }

// ---------------- prep: pack W1..W5 into MFMA-B fragment-linear bf16 layout ----------------
__global__ void prep_weights(const float* __restrict__ W1, const float* __restrict__ W2,
    const float* __restrict__ W3, const float* __restrict__ W4, const float* __restrict__ W5,
    unsigned short* __restrict__ wpack){
  int idx = blockIdx.x*256 + threadIdx.x;
  if (idx >= 22656) return;
  const float* W; int rel; int Kd;
  if (idx < 5760){ W = W1; rel = idx; Kd = 230; }
  else {
    int r2 = idx - 5760;
    int li = r2 / 4224; rel = r2 - li*4224; Kd = 164;
    W = (li==0)?W2:((li==1)?W3:((li==2)?W4:W5));
  }
  int lane = rel & 63, rem = rel >> 6;
  int nt = rem % 6, ks = rem / 6;
  int n  = nt*32 + (lane&31);
  int k0 = ks*16 + ((lane>>5)<<3);
  unsigned int v[4];
  #pragma unroll
  for (int p=0;p<4;p++){
    int ka = k0 + 2*p, kb = ka+1;
    float fa = (ka<Kd && n<164) ? W[ka*164+n] : 0.f;
    float fb = (kb<Kd && n<164) ? W[kb*164+n] : 0.f;
    v[p] = packpair(fa, fb);
  }
  *(uint4*)(wpack + (size_t)idx*8) = make_uint4(v[0],v[1],v[2],v[3]);
}

// ---------------- prep: small-weights image ----------------
// word layout: [0,1380) proj PAIR-packed: pair p (outputs 2p,2p+1) uses 12 words:
//   [2u]=w_even[u], [2u+1]=w_odd[u] (u=0..3), [8]=b_even, [9]=b_odd, [10]=roff (raw u32), [11]=0.
// [1380,1500) M=WqWk^T/sqrt(10) [10][12] f32; [1500,1620) Wv [10][12] f32;
// [1620,2604) head weights f32 [6][164] (k-major).
__global__ void prep_small(const float* __restrict__ Wproj, const float* __restrict__ bproj,
    const float* __restrict__ Wq, const float* __restrict__ Wk, const float* __restrict__ Wv,
    const float* __restrict__ Wmove, const float* __restrict__ Wmark,
    unsigned int* __restrict__ swimg){
  int idx = blockIdx.x*256 + threadIdx.x;
  if (idx >= 2604) return;
  unsigned int outv;
  if (idx < 1380){
    int p = idx/12, rem = idx - p*12;
    int fi = p/5;                    // 5 output-pairs per feature
    int roff = FOFF[fi], dims = FDIM[fi];
    if (rem < 8){
      int u = rem>>1, odd = rem&1;
      float v = (u < dims) ? Wproj[(roff+u)*230 + 2*p+odd] : 0.f;
      outv = __float_as_uint(v);
    } else if (rem < 10){
      outv = __float_as_uint(bproj[2*p + (rem-8)]);
    } else if (rem == 10){
      outv = (unsigned int)roff;
    } else outv = 0u;
  } else if (idx < 1500){
    int r = idx-1380, e = r/12, d = r-12*e;
    float v = 0.f;
    if (d<10){ float ssum=0.f;
      #pragma unroll
      for (int k2=0;k2<10;k2++) ssum += Wq[e*10+k2]*Wk[d*10+k2];
      v = ssum*0.31622776601683794f; }
    outv = __float_as_uint(v);
  } else if (idx < 1620){
    int r = idx-1500, e = r/12, d = r-12*e;
    outv = __float_as_uint((d<10)? Wv[e*10+d] : 0.f);
  } else {
    int r = idx-1620;            // 0..983
    int o = r/164, k = r-o*164;  // k 0..163
    outv = __float_as_uint((o<5)? Wmove[k*5+o] : Wmark[k]);
  }
  swimg[idx] = outv;
}

// ---------------- attention chunk: C (<=2) query rows, h f32 pairs (pitch 32), pipelined ------
// All call sites now pass C=1 (constant-folds: guards vanish, arrays halve). All math f32x2
// (v_pk_fma_f32); 2-deep hjA/hjB prefetch hides ds_read_b64 latency.
__device__ __forceinline__ void attn_chunk2(int s, int ibase, int C,
    const f32x2* hf2, const f32x2* swf2, unsigned int* z32){
  // ---- g = h_i * M ----
  f32x2 g2[2][5];
  #pragma unroll
  for (int c=0;c<2;c++)
    #pragma unroll
    for (int p=0;p<5;p++) g2[c][p] = (f32x2){0.f,0.f};
  {
    f32x2 hi2[2][5];
    #pragma unroll
    for (int c=0;c<2;c++) if (c<C){
      #pragma unroll
      for (int p=0;p<5;p++) hi2[c][p] = hf2[((ibase+c)*5+p)*32 + s];
    }
    #pragma unroll
    for (int e=0;e<10;e++){
      f32x2 m2[5];
      #pragma unroll
      for (int p=0;p<5;p++) m2[p] = swf2[e*6 + p];
      #pragma unroll
      for (int c=0;c<2;c++) if (c<C){
        float he = (e&1) ? hi2[c][e>>1].y : hi2[c][e>>1].x;
        #pragma unroll
        for (int p=0;p<5;p++) g2[c][p] += m2[p]*he;
      }
    }
  }
  // ---- single-pass unnormalized softmax over 23 keys (2-deep pipelined) ----
  f32x2 st2[2][5]; float tau[2];
  #pragma unroll
  for (int c=0;c<2;c++){
    tau[c]=0.f;
    #pragma unroll
    for (int p=0;p<5;p++) st2[c][p] = (f32x2){0.f,0.f};
  }
  f32x2 hjA[5], hjB[5];
  auto keystep = [&](f32x2 (&hj)[5]){
    #pragma unroll
    for (int c=0;c<2;c++) if (c<C){
      f32x2 l2 = g2[c][0]*hj[0];
      #pragma unroll
      for (int p=1;p<5;p++) l2 += g2[c][p]*hj[p];
      float e = __expf(l2.x + l2.y);
      tau[c] += e;
      #pragma unroll
      for (int p=0;p<5;p++) st2[c][p] += hj[p]*e;
    }
  };
  #pragma unroll
  for (int p=0;p<5;p++) hjA[p] = hf2[p*32 + s];                  // j=0
  for (int jj=0; jj<11; ++jj){
    #pragma unroll
    for (int p=0;p<5;p++) hjB[p] = hf2[((2*jj+1)*5+p)*32 + s];   // prefetch odd j
    keystep(hjA);                                                // compute even j
    #pragma unroll
    for (int p=0;p<5;p++) hjA[p] = hf2[((2*jj+2)*5+p)*32 + s];   // prefetch next even (<=22)
    keystep(hjB);                                                // compute odd j
  }
  keystep(hjA);                                                  // j=22
  #pragma unroll
  for (int c=0;c<2;c++) if (c<C){
    float inv = 1.f/tau[c];
    #pragma unroll
    for (int p=0;p<5;p++) st2[c][p] *= inv;
  }
  // ---- ctx = st * Wv ----
  f32x2 ct2[2][5];
  #pragma unroll
  for (int c=0;c<2;c++)
    #pragma unroll
    for (int p=0;p<5;p++) ct2[c][p] = (f32x2){0.f,0.f};
  #pragma unroll
  for (int e=0;e<10;e++){
    f32x2 wv2[5];
    #pragma unroll
    for (int p=0;p<5;p++) wv2[p] = swf2[60 + e*6 + p];
    #pragma unroll
    for (int c=0;c<2;c++) if (c<C){
      float se = (e&1) ? st2[c][e>>1].y : st2[c][e>>1].x;
      #pragma unroll
      for (int p=0;p<5;p++) ct2[c][p] += wv2[p]*se;
    }
  }
  // ---- residual + pack to z (v_cvt_pk_bf16_f32: 1 inst, RNE) ----
  #pragma unroll
  for (int c=0;c<2;c++) if (c<C){
    int i = ibase+c;
    #pragma unroll
    for (int p=0;p<5;p++){
      f32x2 h = hf2[(i*5+p)*32 + s];
      float z0 = h.x + ct2[c][p].x;
      float z1 = h.y + ct2[c][p].y;
      unsigned int r;
      asm volatile("v_cvt_pk_bf16_f32 %0, %1, %2" : "=v"(r) : "v"(z0), "v"(z1));
      z32[s*124 + i*5 + p] = r;
    }
  }
}

// ---------------- MFMA MLP: 32 rows, 6 active waves, 1 N-tile each (N 164->192) --------------
template<int KSTEPS>
__device__ __forceinline__ void mlp_layer(const unsigned short* in16, int inPitch,
    const bf16x8* __restrict__ wp, const float* __restrict__ bias,
    unsigned short* out16, int t){
  const int lane = t & 63;
  const int nt = t >> 6;     // 0..11; only 0..5 carry tiles
  if (nt >= 6) return;
  const unsigned short* abase = in16 + (lane&31)*inPitch + ((lane>>5)<<3);
  const bf16x8* wb = wp + nt*64 + lane;
  f32x16 acc;
  #pragma unroll
  for (int r=0;r<16;r++) acc[r]=0.f;
  #pragma unroll
  for (int ks=0; ks<KSTEPS; ++ks){
    bf16x8 a = *(const bf16x8*)(abase + ks*16);
    acc = __builtin_amdgcn_mfma_f32_32x32x16_bf16(a, wb[ks*(6*64)], acc, 0,0,0);
  }
  const int colb = lane&31;
  const int rowb = 4*(lane>>5);
  int n = nt*32 + colb;
  float b = (n<164) ? bias[n] : 0.f;
  #pragma unroll
  for (int r=0;r<16;r++){
    int row = rowb + (r&3) + 8*(r>>2);
    float v = fmaxf(acc[r] + b, 0.f);
    out16[row*200 + n] = f2bf(v);
  }
}

// ---------------- fused main kernel: 32 samples / 768-thread workgroup, 2 blocks/CU ----------
// Tail-bound diagnosis (R12): kernel runs at ~19% issue efficiency; barriers wait on the
// slowest phase participant. P2's slowest was a C=2 group (2x the C=1 work). Fix: 23 groups of
// 32 threads, ONE row each (C=1 everywhere, constant-folded) -> P2 critical path -46%.
// Residency: 2 x 12 waves = 24 waves/CU; VGPR cap 2048/(2*12)=85 >> need; LDS 2x50,208 fits.
__global__ __launch_bounds__(768, 2) void actor_main(
    const float* __restrict__ xg,
    const float* __restrict__ b1, const float* __restrict__ b2, const float* __restrict__ b3,
    const float* __restrict__ b4, const float* __restrict__ b5,
    const float* __restrict__ bmove, const float* __restrict__ bmark,
    const unsigned short* __restrict__ wpack, float* __restrict__ out)
{
  // LDS: [0,15872) z-buffer (32 x pitch 248 bf16) / {x-stage [0,8352) + proj pairs
  //      [8352,13872)} union / P4-partials union;
  //      [15872,45312) h f32-pair SoA (23*5*32 f32x2) / act buffer union (32 x pitch 200 bf16);
  //      [45312,50208) persistent small weights: M [0,120), Wv [120,240), heads [240,1224) words.
  __shared__ __align__(16) unsigned char LDS[50208];
  float* xb = (float*)LDS;
  unsigned int* xw = (unsigned int*)LDS;
  unsigned int* z32 = (unsigned int*)LDS;
  unsigned short* z16 = (unsigned short*)LDS;
  f32x2* hf2 = (f32x2*)(LDS + 15872);
  unsigned short* a16 = (unsigned short*)(LDS + 15872);
  float* swp = (float*)(LDS + 45312);
  const f32x2* swf2 = (const f32x2*)(LDS + 45312);

  const int t = threadIdx.x;
  const int S0 = blockIdx.x*32;

  // ---- P0: stage x (coalesced float4) + proj pairs into x-region + persistent weights ----
  {
    const float4* src4 = (const float4*)(xg + (size_t)S0*65);
    float4* x4 = (float4*)LDS;
    for (int i=t; i<520; i+=768) x4[i] = src4[i];   // 32*65 = 2080 floats
    if (t<8) xb[2080+t] = 0.f;   // proj over-read pad (zero-weight lanes)
    const unsigned int* swsrc = (const unsigned int*)(wpack + 181248);
    for (int idx=t; idx<1380; idx+=768) xw[2088+idx] = swsrc[idx];        // proj pair words
    for (int idx=t; idx<1224; idx+=768)
      ((unsigned int*)swp)[idx] = swsrc[1380+idx];                        // M/Wv/heads
  }
  __syncthreads();

  // ---- P1: projection via pk_fma pairs -> h f32 pairs hf2[k*32+s], k=0..114 ----
  {
    const f32x2* pw2 = (const f32x2*)(xb + 2088);
    const unsigned int* pwu = (const unsigned int*)(xb + 2088);
    for (int L=t; L<3680; L+=768){
      int s = L & 31, k = L>>5;
      int roff = (int)pwu[k*12 + 10];
      f32x2 acc = pw2[k*6 + 4];          // bias pair
      #pragma unroll
      for (int u=0;u<4;u++){
        float xv = xb[s*65 + roff + u];
        acc += pw2[k*6 + u] * xv;
      }
      hf2[k*32 + s] = acc;
    }
  }
  __syncthreads();

  // ---- P2: attention, 23 groups x 1 row each (perfectly balanced, C=1 const-folded) ----
  {
    const int s = t & 31;
    const int q = t >> 5;            // 0..23
    if (q < 23){
      attn_chunk2(s, q, 1, hf2, swf2, z32);          // row q
    } else {
      // group 23: zero z pad cols 230..239 (K padded to 240 for layer1)
      for (int idx=s; idx<160; idx+=32){
        int ss = idx/5, pc = idx-5*ss;
        z32[ss*124 + 115+pc] = 0u;
      }
    }
  }
  __syncthreads();

  // ---- P3: MLP, 5 layers of MFMA, ping-pong LDS act buffers (final acts in a16) ----
  const bf16x8* wpk = (const bf16x8*)wpack;
  mlp_layer<15>(z16, 248, wpk,          b1, a16, t); __syncthreads();
  mlp_layer<11>(a16, 200, wpk + 5760,   b2, z16, t); __syncthreads();
  mlp_layer<11>(z16, 200, wpk + 9984,   b3, a16, t); __syncthreads();
  mlp_layer<11>(a16, 200, wpk + 14208,  b4, z16, t); __syncthreads();
  mlp_layer<11>(z16, 200, wpk + 18432,  b5, a16, t); __syncthreads();

  // ---- P4: heads, split-k over 24 groups (4 k-quarters x 6 outputs), pk_fma ----
  {
    float* pb = (float*)LDS;   // z region is free now
    {
      int s2 = t & 31, r = t>>5;       // r 0..23
      int o = r>>2, quarter = r&3;     // o 0..5, quarter 0..3
      const uint4* ar4 = (const uint4*)(a16 + s2*200);
      const f32x2* hw = swf2 + 120 + o*82;   // persistent word 240 + o*164, as f32x2
      f32x2 acc2 = {0.f,0.f};
      int q0 = quarter*5, q1 = q0+5;         // uint4 index range (kp = 4*q4..)
      for (int q4=q0; q4<q1; ++q4){
        uint4 v = ar4[q4];
        unsigned int wv[4] = {v.x,v.y,v.z,v.w};
        #pragma unroll
        for (int e=0;e<4;e++){
          f32x2 av; av.x = bflo(wv[e]); av.y = bfhi(wv[e]);
          acc2 += av * hw[q4*4+e];
        }
      }
      if (quarter==3){
        const unsigned int* ar = (const unsigned int*)(a16 + s2*200);
        #pragma unroll
        for (int kp=80;kp<82;kp++){
          unsigned int u = ar[kp];
          f32x2 av; av.x = bflo(u); av.y = bfhi(u);
          acc2 += av * hw[kp];
        }
      }
      pb[r*32 + s2] = acc2.x + acc2.y;
    }
    __syncthreads();
    if (t < 192){
      int s2 = t & 31, o = t>>5;       // o 0..5
      float acc = pb[(4*o)*32 + s2] + pb[(4*o+1)*32 + s2]
                + pb[(4*o+2)*32 + s2] + pb[(4*o+3)*32 + s2];
      acc += (o<5)? bmove[o] : bmark[0];
      if (o<5) out[(size_t)(S0+s2)*5 + o] = acc;
      else     out[(size_t)BATCH*5 + S0 + s2] = acc;
    }
  }
}

extern "C" void kernel_launch(void* const* d_in, const int* in_sizes, int n_in,
                              void* d_out, int out_size, void* d_ws, size_t ws_size,
                              hipStream_t stream){
  (void)in_sizes; (void)n_in; (void)out_size; (void)ws_size;
  const float* x     = (const float*)d_in[0];
  const float* Wproj = (const float*)d_in[1];
  const float* bproj = (const float*)d_in[2];
  const float* Wq    = (const float*)d_in[3];
  const float* Wk    = (const float*)d_in[4];
  const float* Wv    = (const float*)d_in[5];
  const float* W1    = (const float*)d_in[6];
  const float* b1    = (const float*)d_in[7];
  const float* W2    = (const float*)d_in[8];
  const float* b2    = (const float*)d_in[9];
  const float* W3    = (const float*)d_in[10];
  const float* b3    = (const float*)d_in[11];
  const float* W4    = (const float*)d_in[12];
  const float* b4    = (const float*)d_in[13];
  const float* W5    = (const float*)d_in[14];
  const float* b5    = (const float*)d_in[15];
  const float* Wmove = (const float*)d_in[16];
  const float* bmove = (const float*)d_in[17];
  const float* Wmark = (const float*)d_in[18];
  const float* bmark = (const float*)d_in[19];
  unsigned short* wpack = (unsigned short*)d_ws;
  unsigned int* swimg = (unsigned int*)(wpack + 181248);   // after 22656*8 shorts

  prep_weights<<<89, 256, 0, stream>>>(W1, W2, W3, W4, W5, wpack);
  prep_small<<<11, 256, 0, stream>>>(Wproj, bproj, Wq, Wk, Wv, Wmove, Wmark, swimg);
  actor_main<<<4096, 768, 0, stream>>>(x,
      b1, b2, b3, b4, b5, bmove, bmark, wpack, (float*)d_out);
}

// Round 14
// 294.352 us; speedup vs baseline: 1.7037x; 1.7037x over previous
//
#include <hip/hip_runtime.h>

#define BATCH 131072

typedef __attribute__((ext_vector_type(8))) __bf16 bf16x8;
typedef __attribute__((ext_vector_type(16))) float f32x16;
typedef __attribute__((ext_vector_type(2))) float f32x2;

__constant__ int FOFF[23] = {0,4,8,12,16,20,24,28,32,36,40,44,48,50,52,53,57,58,59,60,61,62,63};
__constant__ int FDIM[23] = {4,4,4,4,4,4,4,4,4,4,4,4,2,2,1,4,1,1,1,1,1,1,2};

__device__ __forceinline__ unsigned short f2bf(float f){
  unsigned int u = __float_as_uint(f);
  u += 0x7fffu + ((u>>16)&1u);   // RNE
  return (unsigned short)(u>>16);
}
__device__ __forceinline__ unsigned int packpair(float a, float b){
  return (unsigned int)f2bf(a) | ((unsigned int)f2bf(b)<<16);
}
__device__ __forceinline__ float bflo(unsigned int u){ return __uint_as_float(u<<16); }
__device__ __forceinline__ float bfhi(unsigned int u){ return __uint_as_float(u & 0xffff0000u); }

// ---------------- prep: pack W1..W5 into MFMA-B fragment-linear bf16 layout ----------------
__global__ void prep_weights(const float* __restrict__ W1, const float* __restrict__ W2,
    const float* __restrict__ W3, const float* __restrict__ W4, const float* __restrict__ W5,
    unsigned short* __restrict__ wpack){
  int idx = blockIdx.x*256 + threadIdx.x;
  if (idx >= 22656) return;
  const float* W; int rel; int Kd;
  if (idx < 5760){ W = W1; rel = idx; Kd = 230; }
  else {
    int r2 = idx - 5760;
    int li = r2 / 4224; rel = r2 - li*4224; Kd = 164;
    W = (li==0)?W2:((li==1)?W3:((li==2)?W4:W5));
  }
  int lane = rel & 63, rem = rel >> 6;
  int nt = rem % 6, ks = rem / 6;
  int n  = nt*32 + (lane&31);
  int k0 = ks*16 + ((lane>>5)<<3);
  unsigned int v[4];
  #pragma unroll
  for (int p=0;p<4;p++){
    int ka = k0 + 2*p, kb = ka+1;
    float fa = (ka<Kd && n<164) ? W[ka*164+n] : 0.f;
    float fb = (kb<Kd && n<164) ? W[kb*164+n] : 0.f;
    v[p] = packpair(fa, fb);
  }
  *(uint4*)(wpack + (size_t)idx*8) = make_uint4(v[0],v[1],v[2],v[3]);
}

// ---------------- prep: small-weights image ----------------
// word layout: [0,1380) proj PAIR-packed: pair p (outputs 2p,2p+1) uses 12 words:
//   [2u]=w_even[u], [2u+1]=w_odd[u] (u=0..3), [8]=b_even, [9]=b_odd, [10]=roff (raw u32), [11]=0.
// [1380,1500) M=WqWk^T/sqrt(10) [10][12] f32; [1500,1620) Wv [10][12] f32;
// [1620,2604) head weights f32 [6][164] (k-major).
__global__ void prep_small(const float* __restrict__ Wproj, const float* __restrict__ bproj,
    const float* __restrict__ Wq, const float* __restrict__ Wk, const float* __restrict__ Wv,
    const float* __restrict__ Wmove, const float* __restrict__ Wmark,
    unsigned int* __restrict__ swimg){
  int idx = blockIdx.x*256 + threadIdx.x;
  if (idx >= 2604) return;
  unsigned int outv;
  if (idx < 1380){
    int p = idx/12, rem = idx - p*12;
    int fi = p/5;                    // 5 output-pairs per feature
    int roff = FOFF[fi], dims = FDIM[fi];
    if (rem < 8){
      int u = rem>>1, odd = rem&1;
      float v = (u < dims) ? Wproj[(roff+u)*230 + 2*p+odd] : 0.f;
      outv = __float_as_uint(v);
    } else if (rem < 10){
      outv = __float_as_uint(bproj[2*p + (rem-8)]);
    } else if (rem == 10){
      outv = (unsigned int)roff;
    } else outv = 0u;
  } else if (idx < 1500){
    int r = idx-1380, e = r/12, d = r-12*e;
    float v = 0.f;
    if (d<10){ float ssum=0.f;
      #pragma unroll
      for (int k2=0;k2<10;k2++) ssum += Wq[e*10+k2]*Wk[d*10+k2];
      v = ssum*0.31622776601683794f; }
    outv = __float_as_uint(v);
  } else if (idx < 1620){
    int r = idx-1500, e = r/12, d = r-12*e;
    outv = __float_as_uint((d<10)? Wv[e*10+d] : 0.f);
  } else {
    int r = idx-1620;            // 0..983
    int o = r/164, k = r-o*164;  // k 0..163
    outv = __float_as_uint((o<5)? Wmove[k*5+o] : Wmark[k]);
  }
  swimg[idx] = outv;
}

// ---------------- attention: ONE query row of one sample, h f32 pairs (pitch 16) -------------
// Hardcoded C=1 (no guards, no C-arrays): ~45 live floats, fits the 64-VGPR cap of
// __launch_bounds__(512,4). No manual pipeline: at 8 waves/SIMD, TLP hides ds_read latency.
__device__ __forceinline__ void attn1(int s, int i,
    const f32x2* hf2, const f32x2* swf2, unsigned int* z32){
  // ---- g = h_i * M ----
  f32x2 g2[5];
  #pragma unroll
  for (int p=0;p<5;p++) g2[p] = (f32x2){0.f,0.f};
  {
    f32x2 hi2[5];
    #pragma unroll
    for (int p=0;p<5;p++) hi2[p] = hf2[(i*5+p)*16 + s];
    #pragma unroll
    for (int e=0;e<10;e++){
      float he = (e&1) ? hi2[e>>1].y : hi2[e>>1].x;
      #pragma unroll
      for (int p=0;p<5;p++) g2[p] += swf2[e*6 + p]*he;
    }
  }
  // ---- single-pass unnormalized softmax over 23 keys ----
  f32x2 st2[5]; float tau = 0.f;
  #pragma unroll
  for (int p=0;p<5;p++) st2[p] = (f32x2){0.f,0.f};
  for (int j=0;j<23;j++){
    f32x2 hj[5];
    #pragma unroll
    for (int p=0;p<5;p++) hj[p] = hf2[(j*5+p)*16 + s];
    f32x2 l2 = g2[0]*hj[0];
    #pragma unroll
    for (int p=1;p<5;p++) l2 += g2[p]*hj[p];
    float e = __expf(l2.x + l2.y);
    tau += e;
    #pragma unroll
    for (int p=0;p<5;p++) st2[p] += hj[p]*e;
  }
  {
    float inv = 1.f/tau;
    #pragma unroll
    for (int p=0;p<5;p++) st2[p] *= inv;
  }
  // ---- ctx = st * Wv ----
  f32x2 ct2[5];
  #pragma unroll
  for (int p=0;p<5;p++) ct2[p] = (f32x2){0.f,0.f};
  #pragma unroll
  for (int e=0;e<10;e++){
    float se = (e&1) ? st2[e>>1].y : st2[e>>1].x;
    #pragma unroll
    for (int p=0;p<5;p++) ct2[p] += swf2[60 + e*6 + p]*se;
  }
  // ---- residual + pack to z (v_cvt_pk_bf16_f32: 1 inst, RNE) ----
  #pragma unroll
  for (int p=0;p<5;p++){
    f32x2 h = hf2[(i*5+p)*16 + s];
    float z0 = h.x + ct2[p].x;
    float z1 = h.y + ct2[p].y;
    unsigned int r;
    asm volatile("v_cvt_pk_bf16_f32 %0, %1, %2" : "=v"(r) : "v"(z0), "v"(z1));
    z32[s*124 + i*5 + p] = r;
  }
}

// ---------------- MFMA MLP: 16 real rows on 32-row tiles; 6 active waves, 1 N-tile each ------
// Only acc[0..7] (rows 0..15) are stored: rows 16-31 are garbage (A rows 16-31 read stale LDS)
// and storing them would overflow the act region. Garbage A rows only affect garbage C rows.
template<int KSTEPS>
__device__ __forceinline__ void mlp_layer(const unsigned short* in16, int inPitch,
    const bf16x8* __restrict__ wp, const float* __restrict__ bias,
    unsigned short* out16, int t){
  const int lane = t & 63;
  const int nt = t >> 6;     // 0..7; only 0..5 carry tiles (N 164->192)
  if (nt >= 6) return;
  const unsigned short* abase = in16 + (lane&31)*inPitch + ((lane>>5)<<3);
  const bf16x8* wb = wp + nt*64 + lane;
  f32x16 acc;
  #pragma unroll
  for (int r=0;r<16;r++) acc[r]=0.f;
  #pragma unroll
  for (int ks=0; ks<KSTEPS; ++ks){
    bf16x8 a = *(const bf16x8*)(abase + ks*16);
    acc = __builtin_amdgcn_mfma_f32_32x32x16_bf16(a, wb[ks*(6*64)], acc, 0,0,0);
  }
  const int colb = lane&31;
  const int rowb = 4*(lane>>5);
  int n = nt*32 + colb;
  float b = (n<164) ? bias[n] : 0.f;
  #pragma unroll
  for (int r=0;r<8;r++){             // rows 0..15 only
    int row = rowb + (r&3) + 8*(r>>2);
    float v = fmaxf(acc[r] + b, 0.f);
    out16[row*200 + n] = f2bf(v);
  }
}

// ---------------- fused main kernel: 16 samples / 512-thread workgroup, target 4 blocks/CU ----
// R12 diagnosis: barrier-tail-bound (~19% issue efficiency); P2 wall = 2-row group (23 rows on
// 16 groups). Fix: 16 samples -> (sample,row) units = 368 <= 512 threads, ONE row per thread,
// C=1 hardcoded. LDS 29,344 B -> 4 blocks/CU if unified regs <= 64/wave (arch <= 48); 3-block
// fallback still >= R12 occupancy. R13's 768-thr codegen landmine avoided (proven 512 shape).
__global__ __launch_bounds__(512, 4) void actor_main(
    const float* __restrict__ xg,
    const float* __restrict__ b1, const float* __restrict__ b2, const float* __restrict__ b3,
    const float* __restrict__ b4, const float* __restrict__ b5,
    const float* __restrict__ bmove, const float* __restrict__ bmark,
    const unsigned short* __restrict__ wpack, float* __restrict__ out)
{
  // LDS: [0,9728) z-buffer (16 x pitch 248 bf16 = 7936) / {x 4192 + proj pairs 5520} union /
  //      P4-partials (1536) union;
  //      [9728,24448) h f32-pair SoA (115*16 f32x2 = 14720) / act buffer (16 x pitch 200);
  //      [24448,29344) persistent: M [0,120), Wv [120,240), heads [240,1224) words.
  __shared__ __align__(16) unsigned char LDS[29344];
  float* xb = (float*)LDS;
  unsigned int* xw = (unsigned int*)LDS;
  unsigned int* z32 = (unsigned int*)LDS;
  unsigned short* z16 = (unsigned short*)LDS;
  f32x2* hf2 = (f32x2*)(LDS + 9728);
  unsigned short* a16 = (unsigned short*)(LDS + 9728);
  const f32x2* swf2 = (const f32x2*)(LDS + 24448);
  unsigned int* swpw = (unsigned int*)(LDS + 24448);

  const int t = threadIdx.x;
  const int S0 = blockIdx.x*16;

  // ---- P0: stage x (coalesced float4) + proj pairs into x-region + persistent weights ----
  {
    const float4* src4 = (const float4*)(xg + (size_t)S0*65);
    float4* x4 = (float4*)LDS;
    if (t < 260) x4[t] = src4[t];    // 16*65 = 1040 floats
    if (t<8) xb[1040+t] = 0.f;       // proj over-read pad (zero-weight lanes)
    const unsigned int* swsrc = (const unsigned int*)(wpack + 181248);
    for (int idx=t; idx<1380; idx+=512) xw[1048+idx] = swsrc[idx];        // proj pair words
    for (int idx=t; idx<1224; idx+=512) swpw[idx] = swsrc[1380+idx];      // M/Wv/heads
  }
  __syncthreads();

  // ---- P1: projection via pk_fma pairs -> h f32 pairs hf2[k*16+s], k=0..114 ----
  {
    const f32x2* pw2 = (const f32x2*)(xb + 1048);
    const unsigned int* pwu = (const unsigned int*)(xb + 1048);
    for (int L=t; L<1840; L+=512){
      int s = L & 15, k = L>>4;
      int roff = (int)pwu[k*12 + 10];
      f32x2 acc = pw2[k*6 + 4];          // bias pair
      #pragma unroll
      for (int u=0;u<4;u++){
        float xv = xb[s*65 + roff + u];
        acc += pw2[k*6 + u] * xv;
      }
      hf2[k*16 + s] = acc;
    }
  }
  __syncthreads();

  // ---- P2: attention, ONE (sample,row) unit per thread — perfectly balanced ----
  {
    const int s = t & 15;
    const int row = t >> 4;          // 0..31; rows 0..22 active
    if (row < 23){
      attn1(s, row, hf2, swf2, z32);
    } else {
      // threads 368..511 zero z pad cols 230..239 (80 words)
      for (int idx = t-368; idx < 80; idx += 144){
        int ss = idx/5, pc = idx-5*ss;
        z32[ss*124 + 115+pc] = 0u;
      }
    }
  }
  __syncthreads();

  // ---- P3: MLP, 5 layers of MFMA, ping-pong LDS act buffers (final acts in a16) ----
  const bf16x8* wpk = (const bf16x8*)wpack;
  mlp_layer<15>(z16, 248, wpk,          b1, a16, t); __syncthreads();
  mlp_layer<11>(a16, 200, wpk + 5760,   b2, z16, t); __syncthreads();
  mlp_layer<11>(z16, 200, wpk + 9984,   b3, a16, t); __syncthreads();
  mlp_layer<11>(a16, 200, wpk + 14208,  b4, z16, t); __syncthreads();
  mlp_layer<11>(z16, 200, wpk + 18432,  b5, a16, t); __syncthreads();

  // ---- P4: heads, split-k (6 outputs x 4 k-quarters on 24 groups of 16), pk_fma ----
  {
    float* pb = (float*)LDS;   // z region is free now
    {
      int s2 = t & 15, r = t>>4;       // r 0..31; 0..23 active
      if (r < 24){
        int o = r>>2, quarter = r&3;   // o 0..5, quarter 0..3
        const uint4* ar4 = (const uint4*)(a16 + s2*200);
        const f32x2* hw = swf2 + 120 + o*82;   // persistent word 240 + o*164, as f32x2
        f32x2 acc2 = {0.f,0.f};
        int q0 = quarter*5, q1 = q0+5;
        for (int q4=q0; q4<q1; ++q4){
          uint4 v = ar4[q4];
          unsigned int wv[4] = {v.x,v.y,v.z,v.w};
          #pragma unroll
          for (int e=0;e<4;e++){
            f32x2 av; av.x = bflo(wv[e]); av.y = bfhi(wv[e]);
            acc2 += av * hw[q4*4+e];
          }
        }
        if (quarter==3){
          const unsigned int* ar = (const unsigned int*)(a16 + s2*200);
          #pragma unroll
          for (int kp=80;kp<82;kp++){
            unsigned int u = ar[kp];
            f32x2 av; av.x = bflo(u); av.y = bfhi(u);
            acc2 += av * hw[kp];
          }
        }
        pb[r*16 + s2] = acc2.x + acc2.y;
      }
    }
    __syncthreads();
    if (t < 96){
      int s2 = t & 15, o = t>>4;       // o 0..5
      float acc = pb[(4*o)*16 + s2] + pb[(4*o+1)*16 + s2]
                + pb[(4*o+2)*16 + s2] + pb[(4*o+3)*16 + s2];
      acc += (o<5)? bmove[o] : bmark[0];
      if (o<5) out[(size_t)(S0+s2)*5 + o] = acc;
      else     out[(size_t)BATCH*5 + S0 + s2] = acc;
    }
  }
}

extern "C" void kernel_launch(void* const* d_in, const int* in_sizes, int n_in,
                              void* d_out, int out_size, void* d_ws, size_t ws_size,
                              hipStream_t stream){
  (void)in_sizes; (void)n_in; (void)out_size; (void)ws_size;
  const float* x     = (const float*)d_in[0];
  const float* Wproj = (const float*)d_in[1];
  const float* bproj = (const float*)d_in[2];
  const float* Wq    = (const float*)d_in[3];
  const float* Wk    = (const float*)d_in[4];
  const float* Wv    = (const float*)d_in[5];
  const float* W1    = (const float*)d_in[6];
  const float* b1    = (const float*)d_in[7];
  const float* W2    = (const float*)d_in[8];
  const float* b2    = (const float*)d_in[9];
  const float* W3    = (const float*)d_in[10];
  const float* b3    = (const float*)d_in[11];
  const float* W4    = (const float*)d_in[12];
  const float* b4    = (const float*)d_in[13];
  const float* W5    = (const float*)d_in[14];
  const float* b5    = (const float*)d_in[15];
  const float* Wmove = (const float*)d_in[16];
  const float* bmove = (const float*)d_in[17];
  const float* Wmark = (const float*)d_in[18];
  const float* bmark = (const float*)d_in[19];
  unsigned short* wpack = (unsigned short*)d_ws;
  unsigned int* swimg = (unsigned int*)(wpack + 181248);   // after 22656*8 shorts

  prep_weights<<<89, 256, 0, stream>>>(W1, W2, W3, W4, W5, wpack);
  prep_small<<<11, 256, 0, stream>>>(Wproj, bproj, Wq, Wk, Wv, Wmove, Wmark, swimg);
  actor_main<<<8192, 512, 0, stream>>>(x,
      b1, b2, b3, b4, b5, bmove, bmark, wpack, (float*)d_out);
}

// Round 15
// 265.723 us; speedup vs baseline: 1.8872x; 1.1077x over previous
//
#include <hip/hip_runtime.h>

#define BATCH 131072

typedef __attribute__((ext_vector_type(8))) __bf16 bf16x8;
typedef __attribute__((ext_vector_type(16))) float f32x16;
typedef __attribute__((ext_vector_type(2))) float f32x2;

__constant__ int FOFF[23] = {0,4,8,12,16,20,24,28,32,36,40,44,48,50,52,53,57,58,59,60,61,62,63};
__constant__ int FDIM[23] = {4,4,4,4,4,4,4,4,4,4,4,4,2,2,1,4,1,1,1,1,1,1,2};

__device__ __forceinline__ unsigned short f2bf(float f){
  unsigned int u = __float_as_uint(f);
  u += 0x7fffu + ((u>>16)&1u);   // RNE
  return (unsigned short)(u>>16);
}
__device__ __forceinline__ unsigned int packpair(float a, float b){
  return (unsigned int)f2bf(a) | ((unsigned int)f2bf(b)<<16);
}
__device__ __forceinline__ float bflo(unsigned int u){ return __uint_as_float(u<<16); }
__device__ __forceinline__ float bfhi(unsigned int u){ return __uint_as_float(u & 0xffff0000u); }

// ---------------- prep: pack W1..W5 into MFMA-B fragment-linear bf16 layout ----------------
__global__ void prep_weights(const float* __restrict__ W1, const float* __restrict__ W2,
    const float* __restrict__ W3, const float* __restrict__ W4, const float* __restrict__ W5,
    unsigned short* __restrict__ wpack){
  int idx = blockIdx.x*256 + threadIdx.x;
  if (idx >= 22656) return;
  const float* W; int rel; int Kd;
  if (idx < 5760){ W = W1; rel = idx; Kd = 230; }
  else {
    int r2 = idx - 5760;
    int li = r2 / 4224; rel = r2 - li*4224; Kd = 164;
    W = (li==0)?W2:((li==1)?W3:((li==2)?W4:W5));
  }
  int lane = rel & 63, rem = rel >> 6;
  int nt = rem % 6, ks = rem / 6;
  int n  = nt*32 + (lane&31);
  int k0 = ks*16 + ((lane>>5)<<3);
  unsigned int v[4];
  #pragma unroll
  for (int p=0;p<4;p++){
    int ka = k0 + 2*p, kb = ka+1;
    float fa = (ka<Kd && n<164) ? W[ka*164+n] : 0.f;
    float fb = (kb<Kd && n<164) ? W[kb*164+n] : 0.f;
    v[p] = packpair(fa, fb);
  }
  *(uint4*)(wpack + (size_t)idx*8) = make_uint4(v[0],v[1],v[2],v[3]);
}

// ---------------- prep: small-weights image ----------------
// word layout: [0,1380) proj PAIR-packed: pair p (outputs 2p,2p+1) uses 12 words:
//   [2u]=w_even[u], [2u+1]=w_odd[u] (u=0..3), [8]=b_even, [9]=b_odd, [10]=roff (raw u32), [11]=0.
// [1380,1500) M=WqWk^T/sqrt(10) [10][12] f32; [1500,1620) Wv [10][12] f32;
// [1620,2604) head weights f32 [6][164] (k-major).
__global__ void prep_small(const float* __restrict__ Wproj, const float* __restrict__ bproj,
    const float* __restrict__ Wq, const float* __restrict__ Wk, const float* __restrict__ Wv,
    const float* __restrict__ Wmove, const float* __restrict__ Wmark,
    unsigned int* __restrict__ swimg){
  int idx = blockIdx.x*256 + threadIdx.x;
  if (idx >= 2604) return;
  unsigned int outv;
  if (idx < 1380){
    int p = idx/12, rem = idx - p*12;
    int fi = p/5;                    // 5 output-pairs per feature
    int roff = FOFF[fi], dims = FDIM[fi];
    if (rem < 8){
      int u = rem>>1, odd = rem&1;
      float v = (u < dims) ? Wproj[(roff+u)*230 + 2*p+odd] : 0.f;
      outv = __float_as_uint(v);
    } else if (rem < 10){
      outv = __float_as_uint(bproj[2*p + (rem-8)]);
    } else if (rem == 10){
      outv = (unsigned int)roff;
    } else outv = 0u;
  } else if (idx < 1500){
    int r = idx-1380, e = r/12, d = r-12*e;
    float v = 0.f;
    if (d<10){ float ssum=0.f;
      #pragma unroll
      for (int k2=0;k2<10;k2++) ssum += Wq[e*10+k2]*Wk[d*10+k2];
      v = ssum*0.31622776601683794f; }
    outv = __float_as_uint(v);
  } else if (idx < 1620){
    int r = idx-1500, e = r/12, d = r-12*e;
    outv = __float_as_uint((d<10)? Wv[e*10+d] : 0.f);
  } else {
    int r = idx-1620;            // 0..983
    int o = r/164, k = r-o*164;  // k 0..163
    outv = __float_as_uint((o<5)? Wmove[k*5+o] : Wmark[k]);
  }
  swimg[idx] = outv;
}

// ---------------- attention: ONE query row of one sample, h f32 pairs (pitch 32) -------------
// Hardcoded C=1 (no guards, no C-arrays), tree-form logit dot. ~45 live floats; under the
// (768,2) cap of 85 the compiler has headroom to overlap j-iterations (R14's VGPR-32 codegen
// had zero MLP within the j-loop — that was the regression).
__device__ __forceinline__ void attn1(int s, int i,
    const f32x2* hf2, const f32x2* swf2, unsigned int* z32){
  // ---- g = h_i * M ----
  f32x2 g2[5];
  #pragma unroll
  for (int p=0;p<5;p++) g2[p] = (f32x2){0.f,0.f};
  {
    f32x2 hi2[5];
    #pragma unroll
    for (int p=0;p<5;p++) hi2[p] = hf2[(i*5+p)*32 + s];
    #pragma unroll
    for (int e=0;e<10;e++){
      float he = (e&1) ? hi2[e>>1].y : hi2[e>>1].x;
      #pragma unroll
      for (int p=0;p<5;p++) g2[p] += swf2[e*6 + p]*he;
    }
  }
  // ---- single-pass unnormalized softmax over 23 keys ----
  f32x2 st2[5]; float tau = 0.f;
  #pragma unroll
  for (int p=0;p<5;p++) st2[p] = (f32x2){0.f,0.f};
  for (int j=0;j<23;j++){
    f32x2 hj[5];
    #pragma unroll
    for (int p=0;p<5;p++) hj[p] = hf2[(j*5+p)*32 + s];
    f32x2 l2 = (g2[0]*hj[0] + g2[1]*hj[1]) + (g2[2]*hj[2] + g2[3]*hj[3]) + g2[4]*hj[4];
    float e = __expf(l2.x + l2.y);
    tau += e;
    #pragma unroll
    for (int p=0;p<5;p++) st2[p] += hj[p]*e;
  }
  {
    float inv = 1.f/tau;
    #pragma unroll
    for (int p=0;p<5;p++) st2[p] *= inv;
  }
  // ---- ctx = st * Wv ----
  f32x2 ct2[5];
  #pragma unroll
  for (int p=0;p<5;p++) ct2[p] = (f32x2){0.f,0.f};
  #pragma unroll
  for (int e=0;e<10;e++){
    float se = (e&1) ? st2[e>>1].y : st2[e>>1].x;
    #pragma unroll
    for (int p=0;p<5;p++) ct2[p] += swf2[60 + e*6 + p]*se;
  }
  // ---- residual + pack to z (v_cvt_pk_bf16_f32: 1 inst, RNE) ----
  #pragma unroll
  for (int p=0;p<5;p++){
    f32x2 h = hf2[(i*5+p)*32 + s];
    float z0 = h.x + ct2[p].x;
    float z1 = h.y + ct2[p].y;
    unsigned int r;
    asm volatile("v_cvt_pk_bf16_f32 %0, %1, %2" : "=v"(r) : "v"(z0), "v"(z1));
    z32[s*124 + i*5 + p] = r;
  }
}

// ---------------- MFMA MLP: 32 rows, waves 0-5 take one N-tile each (N 164->192) -------------
template<int KSTEPS>
__device__ __forceinline__ void mlp_layer(const unsigned short* in16, int inPitch,
    const bf16x8* __restrict__ wp, const float* __restrict__ bias,
    unsigned short* out16, int t){
  const int lane = t & 63;
  const int nt = t >> 6;     // 0..11; only 0..5 carry tiles
  if (nt >= 6) return;
  const unsigned short* abase = in16 + (lane&31)*inPitch + ((lane>>5)<<3);
  const bf16x8* wb = wp + nt*64 + lane;
  f32x16 acc;
  #pragma unroll
  for (int r=0;r<16;r++) acc[r]=0.f;
  #pragma unroll
  for (int ks=0; ks<KSTEPS; ++ks){
    bf16x8 a = *(const bf16x8*)(abase + ks*16);
    acc = __builtin_amdgcn_mfma_f32_32x32x16_bf16(a, wb[ks*(6*64)], acc, 0,0,0);
  }
  const int colb = lane&31;
  const int rowb = 4*(lane>>5);
  int n = nt*32 + colb;
  float b = (n<164) ? bias[n] : 0.f;
  #pragma unroll
  for (int r=0;r<16;r++){
    int row = rowb + (r&3) + 8*(r>>2);
    float v = fmaxf(acc[r] + b, 0.f);
    out16[row*200 + n] = f2bf(v);
  }
}

// ---------------- fused main kernel: 32 samples / 768-thread workgroup, 2 blocks/CU ----------
// Synthesis of R12 (32 samples: full MFMA tiles, 24 waves/CU) and R14 (one (sample,row) unit
// per thread: balanced P2). 32x23=736 <= 768. (768,2) -> VGPR cap 85 (R13 measured 84): lean
// attn1 (~45 live) fits with ILP headroom; 2 blocks x 12 waves = 24 waves/CU needs arch <= 69.
// R13's spill was the C=2+pipelined body at this cap — attn1 measured 32 VGPR at 512-thr.
__global__ __launch_bounds__(768, 2) void actor_main(
    const float* __restrict__ xg,
    const float* __restrict__ b1, const float* __restrict__ b2, const float* __restrict__ b3,
    const float* __restrict__ b4, const float* __restrict__ b5,
    const float* __restrict__ bmove, const float* __restrict__ bmark,
    const unsigned short* __restrict__ wpack, float* __restrict__ out)
{
  // LDS: [0,15872) z-buffer (32 x pitch 248 bf16) / {x 8352 + proj pairs 5520} union /
  //      P4-partials (3072) union;
  //      [15872,45312) h f32-pair SoA (115*32 f32x2) / act buffer (32 x pitch 200 bf16);
  //      [45312,50208) persistent: M [0,120), Wv [120,240), heads [240,1224) words.
  __shared__ __align__(16) unsigned char LDS[50208];
  float* xb = (float*)LDS;
  unsigned int* xw = (unsigned int*)LDS;
  unsigned int* z32 = (unsigned int*)LDS;
  unsigned short* z16 = (unsigned short*)LDS;
  f32x2* hf2 = (f32x2*)(LDS + 15872);
  unsigned short* a16 = (unsigned short*)(LDS + 15872);
  const f32x2* swf2 = (const f32x2*)(LDS + 45312);
  unsigned int* swpw = (unsigned int*)(LDS + 45312);

  const int t = threadIdx.x;
  const int S0 = blockIdx.x*32;

  // ---- P0: stage x (coalesced float4) + proj pairs into x-region + persistent weights ----
  {
    const float4* src4 = (const float4*)(xg + (size_t)S0*65);
    float4* x4 = (float4*)LDS;
    if (t < 520) x4[t] = src4[t];    // 32*65 = 2080 floats
    if (t<8) xb[2080+t] = 0.f;       // proj over-read pad (zero-weight lanes)
    const unsigned int* swsrc = (const unsigned int*)(wpack + 181248);
    for (int idx=t; idx<1380; idx+=768) xw[2088+idx] = swsrc[idx];        // proj pair words
    for (int idx=t; idx<1224; idx+=768) swpw[idx] = swsrc[1380+idx];      // M/Wv/heads
  }
  __syncthreads();

  // ---- P1: projection via pk_fma pairs -> h f32 pairs hf2[k*32+s], k=0..114 ----
  {
    const f32x2* pw2 = (const f32x2*)(xb + 2088);
    const unsigned int* pwu = (const unsigned int*)(xb + 2088);
    for (int L=t; L<3680; L+=768){
      int s = L & 31, k = L>>5;
      int roff = (int)pwu[k*12 + 10];
      f32x2 acc = pw2[k*6 + 4];          // bias pair
      #pragma unroll
      for (int u=0;u<4;u++){
        float xv = xb[s*65 + roff + u];
        acc += pw2[k*6 + u] * xv;
      }
      hf2[k*32 + s] = acc;
    }
  }
  __syncthreads();

  // ---- P2: attention, ONE (sample,row) unit per thread — balanced, C=1 hardcoded ----
  {
    const int s = t & 31;
    const int row = t >> 5;          // 0..23; rows 0..22 active
    if (row < 23){
      attn1(s, row, hf2, swf2, z32);
    } else {
      // group 23 (half of wave 11): zero z pad cols 230..239 (160 words)
      for (int idx = s; idx < 160; idx += 32){
        int ss = idx/5, pc = idx-5*ss;
        z32[ss*124 + 115+pc] = 0u;
      }
    }
  }
  __syncthreads();

  // ---- P3: MLP, 5 layers of MFMA, ping-pong LDS act buffers (final acts in a16) ----
  const bf16x8* wpk = (const bf16x8*)wpack;
  mlp_layer<15>(z16, 248, wpk,          b1, a16, t); __syncthreads();
  mlp_layer<11>(a16, 200, wpk + 5760,   b2, z16, t); __syncthreads();
  mlp_layer<11>(z16, 200, wpk + 9984,   b3, a16, t); __syncthreads();
  mlp_layer<11>(a16, 200, wpk + 14208,  b4, z16, t); __syncthreads();
  mlp_layer<11>(z16, 200, wpk + 18432,  b5, a16, t); __syncthreads();

  // ---- P4: heads, split-k: 768 units = 32 samples x 6 outputs x 4 k-quarters, pk_fma ----
  {
    float* pb = (float*)LDS;   // z region is free now
    {
      int s2 = t & 31, r = t>>5;       // r 0..23
      int o = r>>2, quarter = r&3;     // o 0..5, quarter 0..3
      const uint4* ar4 = (const uint4*)(a16 + s2*200);
      const f32x2* hw = swf2 + 120 + o*82;   // persistent word 240 + o*164, as f32x2
      f32x2 acc2 = {0.f,0.f};
      int q0 = quarter*5, q1 = q0+5;
      for (int q4=q0; q4<q1; ++q4){
        uint4 v = ar4[q4];
        unsigned int wv[4] = {v.x,v.y,v.z,v.w};
        #pragma unroll
        for (int e=0;e<4;e++){
          f32x2 av; av.x = bflo(wv[e]); av.y = bfhi(wv[e]);
          acc2 += av * hw[q4*4+e];
        }
      }
      if (quarter==3){
        const unsigned int* ar = (const unsigned int*)(a16 + s2*200);
        #pragma unroll
        for (int kp=80;kp<82;kp++){
          unsigned int u = ar[kp];
          f32x2 av; av.x = bflo(u); av.y = bfhi(u);
          acc2 += av * hw[kp];
        }
      }
      pb[r*32 + s2] = acc2.x + acc2.y;
    }
    __syncthreads();
    if (t < 192){
      int s2 = t & 31, o = t>>5;       // o 0..5
      float acc = pb[(4*o)*32 + s2] + pb[(4*o+1)*32 + s2]
                + pb[(4*o+2)*32 + s2] + pb[(4*o+3)*32 + s2];
      acc += (o<5)? bmove[o] : bmark[0];
      if (o<5) out[(size_t)(S0+s2)*5 + o] = acc;
      else     out[(size_t)BATCH*5 + S0 + s2] = acc;
    }
  }
}

extern "C" void kernel_launch(void* const* d_in, const int* in_sizes, int n_in,
                              void* d_out, int out_size, void* d_ws, size_t ws_size,
                              hipStream_t stream){
  (void)in_sizes; (void)n_in; (void)out_size; (void)ws_size;
  const float* x     = (const float*)d_in[0];
  const float* Wproj = (const float*)d_in[1];
  const float* bproj = (const float*)d_in[2];
  const float* Wq    = (const float*)d_in[3];
  const float* Wk    = (const float*)d_in[4];
  const float* Wv    = (const float*)d_in[5];
  const float* W1    = (const float*)d_in[6];
  const float* b1    = (const float*)d_in[7];
  const float* W2    = (const float*)d_in[8];
  const float* b2    = (const float*)d_in[9];
  const float* W3    = (const float*)d_in[10];
  const float* b3    = (const float*)d_in[11];
  const float* W4    = (const float*)d_in[12];
  const float* b4    = (const float*)d_in[13];
  const float* W5    = (const float*)d_in[14];
  const float* b5    = (const float*)d_in[15];
  const float* Wmove = (const float*)d_in[16];
  const float* bmove = (const float*)d_in[17];
  const float* Wmark = (const float*)d_in[18];
  const float* bmark = (const float*)d_in[19];
  unsigned short* wpack = (unsigned short*)d_ws;
  unsigned int* swimg = (unsigned int*)(wpack + 181248);   // after 22656*8 shorts

  prep_weights<<<89, 256, 0, stream>>>(W1, W2, W3, W4, W5, wpack);
  prep_small<<<11, 256, 0, stream>>>(Wproj, bproj, Wq, Wk, Wv, Wmove, Wmark, swimg);
  actor_main<<<4096, 768, 0, stream>>>(x,
      b1, b2, b3, b4, b5, bmove, bmark, wpack, (float*)d_out);
}